// Round 3
// baseline (170.674 us; speedup 1.0000x reference)
//
#include <hip/hip_runtime.h>
#include <hip/hip_bf16.h>
#include <math.h>

// Problem constants
#define NWL    296
#define FMD    74          // pooled feature dim
#define HEAD   64
#define EMBD   48
#define BATCH  2048
#define XCOLS  300
#define NPAIR  2701        // 74*73/2 upper-triangle pairs
#define NPAIR_P 3072       // padded to KSPLIT*KCH multiple (dummy pairs have wA=0)
#define KSPLIT 4
#define SEGLEN (NPAIR_P / KSPLIT)  // 768
#define KCH    128         // pair chunk per LDS pass
#define TB     8           // batch rows per main block
#define ROWBLKS (BATCH / TB)       // 256

// Workspace float offsets (total 859,776 floats = 3.28 MB)
#define WS_WAT  0                        // [NPAIR_P][64] antisym NDI weights /16
#define WS_CMR  (NPAIR_P * HEAD)         // 196608: [74][64] colsum-rowsum of wDI
#define WS_PAIR (WS_CMR + FMD * HEAD)    // 201344: [NPAIR_P] u32 (4I | 4J<<16)
#define WS_PDI  (WS_PAIR + NPAIR_P)      // 204416: [BATCH][64] DI head partial
#define WS_PNDI (WS_PDI + BATCH * HEAD)  // 335488: [KSPLIT][BATCH][64] NDI partials

__device__ __forceinline__ float eluf(float x) { return x > 0.f ? x : expm1f(x); }

// ---------------------------------------------------------------------------
// prep: pair index table, folded DI weights cmr[K][h], antisym NDI wAT[k][h]
// grid = 768 blocks * 256 = 196608 threads = NPAIR_P*64 exactly
// ---------------------------------------------------------------------------
__global__ __launch_bounds__(256) void fcr_prep_v3(
    const float* __restrict__ wDI,
    const float* __restrict__ wNDI,
    float* __restrict__ ws) {
  int idx = blockIdx.x * 256 + threadIdx.x;

  if (idx < NPAIR_P) {
    unsigned pb = 0;
    if (idx < NPAIR) {
      int rem = idx, I = 0;
      while (rem >= 73 - I) { rem -= 73 - I; I++; }
      int J = I + 1 + rem;
      pb = (unsigned)(4 * I) | ((unsigned)(4 * J) << 16);
    }
    ((unsigned*)(ws + WS_PAIR))[idx] = pb;
  }

  if (idx < FMD * HEAD) {  // cmr[K][h] = sum_I wDI[h][I][K] - sum_J wDI[h][K][J]
    int K = idx >> 6, h = idx & 63;
    const float* w = wDI + h * (FMD * FMD);
    float cs = 0.f, rs = 0.f;
    for (int I = 0; I < FMD; I++) {
      cs += w[I * FMD + K];
      rs += w[K * FMD + I];
    }
    ws[WS_CMR + idx] = cs - rs;
  }

  {  // wAT[k][h] = (wNDI[h][I][J] - wNDI[h][J][I]) / 16   (pool mean folded in)
    int k = idx >> 6, h = idx & 63;
    float v = 0.f;
    if (k < NPAIR) {
      int rem = k, I = 0;
      while (rem >= 73 - I) { rem -= 73 - I; I++; }
      int J = I + 1 + rem;
      const float* w = wNDI + h * (FMD * FMD);
      v = (w[I * FMD + J] - w[J * FMD + I]) * 0.0625f;
    }
    ws[WS_WAT + idx] = v;
  }
}

// ---------------------------------------------------------------------------
// main: per block: 8 batch rows x one K-segment of pairs.
// Computes S[b,pair] = sum_{4x4} (u-v)/(u+v+eps) on the fly in LDS chunks,
// contracts against wAT; seg 0 also does the separable DI einsum.
// grid = ROWBLKS*KSPLIT = 1024 blocks
// ---------------------------------------------------------------------------
__global__ __launch_bounds__(256) void fcr_main_v3(
    const float* __restrict__ x,
    float* __restrict__ ws) {
  __shared__ float xs[TB][308];   // 308: 16B-aligned rows, stride 20 mod 32 (no bank clash)
  __shared__ float xs4[TB][FMD];
  __shared__ float Sm[KCH][TB];

  const unsigned* pairB = (const unsigned*)(ws + WS_PAIR);
  const float* wAT = ws + WS_WAT;
  const float* cmr = ws + WS_CMR;
  float* pDI  = ws + WS_PDI;
  float* pNDI = ws + WS_PNDI;

  int t = threadIdx.x;
  int bid = blockIdx.x;
  int seg = bid & (KSPLIT - 1);
  int rowblk = bid >> 2;
  int row0 = rowblk * TB;

  // stage x rows: fp32, float4-vectorized (row stride 300 floats -> 16B aligned)
  for (int i = t; i < TB * (NWL / 4); i += 256) {
    int r = i / (NWL / 4), c4 = i - r * (NWL / 4);
    float4 v = *(const float4*)(x + (size_t)(row0 + r) * XCOLS + 4 * c4);
    *(float4*)&xs[r][4 * c4] = v;
  }
  __syncthreads();

  // 4-pooled x
  for (int i = t; i < TB * FMD; i += 256) {
    int r = i / FMD, K = i - r * FMD;
    xs4[r][K] = 0.25f * (xs[r][4*K] + xs[r][4*K+1] + xs[r][4*K+2] + xs[r][4*K+3]);
  }
  __syncthreads();

  int h = t & 63;
  int r4 = t >> 6;                 // wave-uniform row offset 0..3 (rows r4 and r4+4)
  float accN0 = 0.f, accN1 = 0.f;

  if (seg == 0) {                  // separable DI path, done once
    float accD0 = 0.f, accD1 = 0.f;
    for (int K = 0; K < FMD; K++) {
      float w = cmr[K * 64 + h];
      accD0 = fmaf(xs4[r4][K], w, accD0);
      accD1 = fmaf(xs4[r4 + 4][K], w, accD1);
    }
    int row = row0 + r4;
    pDI[row * 64 + h] = accD0;
    pDI[(row + 4) * 64 + h] = accD1;
  }

  int kcA = t >> 3, rA = t & 7;
  int k0 = seg * SEGLEN;

  for (int chunk = 0; chunk < SEGLEN; chunk += KCH) {
    // ---- phase A: 128 pairs x 8 rows of pooled ratio sums into LDS ----
    #pragma unroll
    for (int p = 0; p < 4; p++) {
      int kc = kcA + p * 32;
      unsigned pb = pairB[k0 + chunk + kc];
      int bI = pb & 0xFFFF, bJ = pb >> 16;
      float4 uv = *(const float4*)&xs[rA][bJ];
      float4 vv = *(const float4*)&xs[rA][bI];
      float u2[4] = { fmaf(2.f, uv.x, 1e-5f), fmaf(2.f, uv.y, 1e-5f),
                      fmaf(2.f, uv.z, 1e-5f), fmaf(2.f, uv.w, 1e-5f) };
      float u[4]  = { uv.x, uv.y, uv.z, uv.w };
      float v[4]  = { vv.x, vv.y, vv.z, vv.w };
      float s = 0.f;
      // (u-v)/(u+v+eps) = (2u+eps)*rcp(u+v+eps) - 1  -> add+rcp+fma per term
      #pragma unroll
      for (int a = 0; a < 4; a++) {
        float va = v[a] + 1e-5f;
        #pragma unroll
        for (int b = 0; b < 4; b++) {
          float den = u[b] + va;
          s = fmaf(u2[b], __builtin_amdgcn_rcpf(den), s);
        }
      }
      Sm[kc][rA] = s - 16.f;
    }
    __syncthreads();

    // ---- phase B: contract chunk against wAT (broadcast LDS reads) ----
    const float* wp = wAT + (size_t)(k0 + chunk) * 64 + h;
    #pragma unroll 8
    for (int kc = 0; kc < KCH; kc++) {
      float wv = wp[kc * 64];
      accN0 = fmaf(Sm[kc][r4], wv, accN0);
      accN1 = fmaf(Sm[kc][r4 + 4], wv, accN1);
    }
    __syncthreads();
  }

  int row = row0 + r4;
  pNDI[((size_t)seg * BATCH + row) * 64 + h] = accN0;
  pNDI[((size_t)seg * BATCH + row + 4) * 64 + h] = accN1;
}

// ---------------------------------------------------------------------------
// tail: reduce K-partials, biases+elu, fcDI/fcNDI (64->48 each), concat(96),
// fc1(96->48), l1(48->20), l2(20->1), sigmoid. Weights LDS-staged TRANSPOSED
// so inner-loop lanes hit consecutive banks. grid = BATCH/TB = 256 blocks.
// Output is FLOAT32 (reference output dtype).
// ---------------------------------------------------------------------------
__global__ __launch_bounds__(256) void fcr_tail_v3(
    const float* __restrict__ ws,
    const float* __restrict__ bDI,
    const float* __restrict__ fcDI_w,
    const float* __restrict__ fcDI_b,
    const float* __restrict__ bNDI,
    const float* __restrict__ fcNDI_w,
    const float* __restrict__ fcNDI_b,
    const float* __restrict__ fc1_w,
    const float* __restrict__ fc1_b,
    const float* __restrict__ l1_w,
    const float* __restrict__ l1_b,
    const float* __restrict__ l2_w,
    const float* __restrict__ l2_b,
    float* __restrict__ out) {
  __shared__ float wDT[HEAD * EMBD];   // [h][o]
  __shared__ float wNT[HEAD * EMBD];   // [h][o]
  __shared__ float w1T[96 * 48];       // [i][o]
  __shared__ float wl1T[48 * 20];      // [j][o]
  __shared__ float wl2s[20];
  __shared__ float bD[HEAD], bN[HEAD], bDe[EMBD], bNe[EMBD], b1[48], bl1s[20];
  __shared__ float bl2s;
  __shared__ float ehD[TB][68], ehN[TB][68];  // pad 68: stride 4 mod 32
  __shared__ float e2[TB][100];               // pad 100: stride 4 mod 32
  __shared__ float e3[TB][52];
  __shared__ float e4[TB][20];

  int t = threadIdx.x;
  for (int i = t; i < HEAD * EMBD; i += 256) {
    int o = i >> 6, hh = i & 63;               // fcDI_w[o][hh]
    wDT[hh * EMBD + o] = fcDI_w[i];
    wNT[hh * EMBD + o] = fcNDI_w[i];
  }
  for (int i = t; i < 48 * 96; i += 256) {
    int o = i / 96, j = i - o * 96;            // fc1_w[o][j]
    w1T[j * 48 + o] = fc1_w[i];
  }
  for (int i = t; i < 20 * 48; i += 256) {
    int o = i / 48, j = i - o * 48;            // l1_w[o][j]
    wl1T[j * 20 + o] = l1_w[i];
  }
  if (t < 20)   { wl2s[t] = l2_w[t]; bl1s[t] = l1_b[t]; }
  if (t < HEAD) { bD[t] = bDI[t]; bN[t] = bNDI[t]; }
  if (t < EMBD) { bDe[t] = fcDI_b[t]; bNe[t] = fcNDI_b[t]; }
  if (t < 48)   b1[t] = fc1_b[t];
  if (t == 0)   bl2s = l2_b[0];

  const float* pDI  = ws + WS_PDI;
  const float* pNDI = ws + WS_PNDI;
  int row0 = blockIdx.x * TB;
  __syncthreads();

  // reduce partials + bias + elu
  for (int i = t; i < TB * HEAD; i += 256) {
    int r = i >> 6, hh = i & 63;
    int row = row0 + r;
    float hD = pDI[row * 64 + hh] + bD[hh];
    float hN = bN[hh];
    for (int s2 = 0; s2 < KSPLIT; s2++)
      hN += pNDI[((size_t)s2 * BATCH + row) * 64 + hh];
    ehD[r][hh] = eluf(hD);
    ehN[r][hh] = eluf(hN);
  }
  __syncthreads();

  // eDI / eNDI -> e2[r][0..95] (concat order: DI then NDI)
  for (int i = t; i < TB * 96; i += 256) {
    int r = i / 96, o = i - r * 96;
    int isN = o >= 48;
    int o2 = isN ? o - 48 : o;
    const float* wb = isN ? wNT : wDT;
    const float* eb = isN ? &ehN[r][0] : &ehD[r][0];
    float s = isN ? bNe[o2] : bDe[o2];
    for (int hh = 0; hh < 64; hh++)
      s = fmaf(eb[hh], wb[hh * EMBD + o2], s);
    e2[r][o] = eluf(s);
  }
  __syncthreads();

  for (int i = t; i < TB * 48; i += 256) {
    int r = i / 48, o = i - r * 48;
    float s = b1[o];
    for (int j = 0; j < 96; j++)
      s = fmaf(e2[r][j], w1T[j * 48 + o], s);
    e3[r][o] = eluf(s);
  }
  __syncthreads();

  if (t < TB * 20) {
    int r = t / 20, o = t - r * 20;
    float s = bl1s[o];
    for (int j = 0; j < 48; j++)
      s = fmaf(e3[r][j], wl1T[j * 20 + o], s);
    e4[r][o] = eluf(s);
  }
  __syncthreads();

  if (t < TB) {
    float s = bl2s;
    for (int j = 0; j < 20; j++)
      s = fmaf(e4[t][j], wl2s[j], s);
    out[row0 + t] = 1.f / (1.f + expf(-s));   // fp32 output
  }
}

extern "C" void kernel_launch(void* const* d_in, const int* in_sizes, int n_in,
                              void* d_out, int out_size, void* d_ws, size_t ws_size,
                              hipStream_t stream) {
  const float* x      = (const float*)d_in[0];
  const float* wDI    = (const float*)d_in[1];
  const float* bDI    = (const float*)d_in[2];
  const float* fcDI_w = (const float*)d_in[3];
  const float* fcDI_b = (const float*)d_in[4];
  const float* wNDI   = (const float*)d_in[5];
  const float* bNDI   = (const float*)d_in[6];
  const float* fcNDI_w= (const float*)d_in[7];
  const float* fcNDI_b= (const float*)d_in[8];
  const float* fc1_w  = (const float*)d_in[9];
  const float* fc1_b  = (const float*)d_in[10];
  const float* l1_w   = (const float*)d_in[11];
  const float* l1_b   = (const float*)d_in[12];
  const float* l2_w   = (const float*)d_in[13];
  const float* l2_b   = (const float*)d_in[14];
  float* out = (float*)d_out;        // reference output dtype = float32
  float* ws = (float*)d_ws;          // uses 3.28 MB of d_ws

  fcr_prep_v3<<<768, 256, 0, stream>>>(wDI, wNDI, ws);
  fcr_main_v3<<<ROWBLKS * KSPLIT, 256, 0, stream>>>(x, ws);
  fcr_tail_v3<<<BATCH / TB, 256, 0, stream>>>(ws, bDI, fcDI_w, fcDI_b,
      bNDI, fcNDI_w, fcNDI_b, fc1_w, fc1_b, l1_w, l1_b, l2_w, l2_b, out);
}

// Round 4
// 133.249 us; speedup vs baseline: 1.2809x; 1.2809x over previous
//
#include <hip/hip_runtime.h>
#include <hip/hip_bf16.h>
#include <math.h>

// Problem constants
#define NWL    296
#define FMD    74          // pooled feature dim
#define HEAD   64
#define EMBD   48
#define BATCH  2048
#define XCOLS  300
#define NPAIR  2701        // 74*73/2 upper-triangle pairs
#define NPAIR_P 3072       // padded; dummy pairs have wA=0
#define KSPLIT 4
#define SEGLEN (NPAIR_P / KSPLIT)  // 768 pairs per segment
#define KCH    256         // pairs per LDS chunk (Sm tile)
#define MROWS  16          // batch rows per main block (MFMA M)
#define TB     8           // batch rows per tail block

// Workspace float offsets (total 761,472 floats = 3.05 MB)
#define WS_CMR  0                          // [74][64] colsum-rowsum of wDI
#define WS_PAIR (FMD * HEAD)               // 4736: [NPAIR_P] u32 (4I | 4J<<16)
#define WS_PDI  (WS_PAIR + NPAIR_P)        // 7808: [BATCH][64] DI head result
#define WS_PNDI (WS_PDI + BATCH * HEAD)    // 138880: [KSPLIT][BATCH][64] NDI partials
#define WS_WATT (WS_PNDI + KSPLIT * BATCH * HEAD)  // 663168: [64][3072] fp16 wAT^T

typedef _Float16 f16x8 __attribute__((ext_vector_type(8)));
typedef float f32x4 __attribute__((ext_vector_type(4)));

__device__ __forceinline__ float eluf(float x) { return x > 0.f ? x : expm1f(x); }

// decode pair index k -> (I,J), I<J, row-major upper triangle
__device__ __forceinline__ void pair_decode(int k, int& I, int& J) {
  I = (int)((147.0f - sqrtf(21609.0f - 8.0f * (float)k)) * 0.5f);
  int base = (I * (147 - I)) >> 1;
  while (base > k) { I--; base = (I * (147 - I)) >> 1; }
  while (I < 72 && ((I + 1) * (146 - I)) / 2 <= k) { I++; base = (I * (147 - I)) >> 1; }
  J = I + 1 + (k - base);
}

// ---------------------------------------------------------------------------
// prep: one block per head h. Coalesced float4 staging of wDI[h], wNDI[h] to
// LDS, then: cmr[K][h] (folded DI weights), wATt[h][k] fp16 (antisym NDI
// weights /16, transposed = MFMA B-fragment row order), pair table (block 0).
// ---------------------------------------------------------------------------
__global__ __launch_bounds__(256) void fcr_prep_v4(
    const float* __restrict__ wDI,
    const float* __restrict__ wNDI,
    float* __restrict__ ws) {
  __shared__ float wdL[FMD * FMD];   // 5476 floats
  __shared__ float wnL[FMD * FMD];

  int t = threadIdx.x;
  int h = blockIdx.x;

  const float4* gd = (const float4*)(wDI + (size_t)h * FMD * FMD);
  const float4* gn = (const float4*)(wNDI + (size_t)h * FMD * FMD);
  for (int i = t; i < FMD * FMD / 4; i += 256) {   // 1369 float4
    ((float4*)wdL)[i] = gd[i];
    ((float4*)wnL)[i] = gn[i];
  }
  __syncthreads();

  // wATt[h][k] fp16
  _Float16* wATt = (_Float16*)(ws + WS_WATT);
  for (int k = t; k < NPAIR_P; k += 256) {
    float v = 0.f;
    if (k < NPAIR) {
      int I, J; pair_decode(k, I, J);
      v = (wnL[I * FMD + J] - wnL[J * FMD + I]) * 0.0625f;
    }
    wATt[(size_t)h * NPAIR_P + k] = (_Float16)v;
  }

  // cmr[K][h] = colsum - rowsum of wDI[h]
  if (t < FMD) {
    int K = t;
    float cs = 0.f, rs = 0.f;
    for (int I = 0; I < FMD; I++) {
      cs += wdL[I * FMD + K];
      rs += wdL[K * FMD + I];
    }
    ws[WS_CMR + K * 64 + h] = cs - rs;
  }

  // pair table (float-index bytes: 4I | 4J<<16), written once
  if (h == 0) {
    unsigned* P = (unsigned*)(ws + WS_PAIR);
    for (int k = t; k < NPAIR_P; k += 256) {
      unsigned pb = 0;
      if (k < NPAIR) {
        int I, J; pair_decode(k, I, J);
        pb = (unsigned)(4 * I) | ((unsigned)(4 * J) << 16);
      }
      P[k] = pb;
    }
  }
}

// ---------------------------------------------------------------------------
// main: block = 16 batch rows x one K-segment (768 pairs). Phase A computes
// S[m][k] = sum_{4x4}(u-v)/(u+v+eps) into LDS as fp16 in MFMA A-frag row
// order; phase B does mfma_f32_16x16x32_f16 against global wATt (B-frag =
// direct 16B loads, L2-resident). Seg-0 blocks also do the separable DI path
// in fp32 VALU. grid = (2048/16)*4 = 512 blocks.
// ---------------------------------------------------------------------------
__global__ __launch_bounds__(256) void fcr_main_v4(
    const float* __restrict__ x,
    float* __restrict__ ws) {
  __shared__ float xs[MROWS][308];       // row stride 308 floats (16B aligned)
  __shared__ float xs4[MROWS][FMD];
  __shared__ _Float16 Sm[MROWS][264];    // 256 k + 8 pad; stride 528B (16B mult)
  __shared__ unsigned pairsL[SEGLEN];

  const unsigned* pairG = (const unsigned*)(ws + WS_PAIR);
  const _Float16* wATt = (const _Float16*)(ws + WS_WATT);
  const float* cmr = ws + WS_CMR;
  float* pDI  = ws + WS_PDI;
  float* pNDI = ws + WS_PNDI;

  int t = threadIdx.x;
  int seg = blockIdx.x & (KSPLIT - 1);
  int row0 = (blockIdx.x >> 2) * MROWS;
  int k0 = seg * SEGLEN;

  // stage x rows (float4; row stride 300 floats = 16B multiple)
  for (int i = t; i < MROWS * (NWL / 4); i += 256) {
    int r = i / (NWL / 4), c4 = i - r * (NWL / 4);
    *(float4*)&xs[r][4 * c4] = *(const float4*)(x + (size_t)(row0 + r) * XCOLS + 4 * c4);
  }
  // stage this segment's pair table
  for (int i = t; i < SEGLEN; i += 256) pairsL[i] = pairG[k0 + i];
  __syncthreads();

  // 4-pooled x
  for (int i = t; i < MROWS * FMD; i += 256) {
    int r = i / FMD, K = i - r * FMD;
    xs4[r][K] = 0.25f * (xs[r][4*K] + xs[r][4*K+1] + xs[r][4*K+2] + xs[r][4*K+3]);
  }
  __syncthreads();

  int lane = t & 63;
  int wv   = t >> 6;          // wave id 0..3 = n-tile
  int n_in = lane & 15;
  int quad = lane >> 4;
  int h    = wv * 16 + n_in;  // this lane's output head column

  // separable DI path (fp32, exact), seg-0 blocks only
  if (seg == 0) {
    int g = wv;               // 4 rows per thread-group
    float a0 = 0.f, a1 = 0.f, a2 = 0.f, a3 = 0.f;
    int hh = lane;            // 64 head lanes
    for (int K = 0; K < FMD; K++) {
      float w = cmr[K * 64 + hh];
      a0 = fmaf(xs4[g*4+0][K], w, a0);
      a1 = fmaf(xs4[g*4+1][K], w, a1);
      a2 = fmaf(xs4[g*4+2][K], w, a2);
      a3 = fmaf(xs4[g*4+3][K], w, a3);
    }
    pDI[(size_t)(row0 + g*4 + 0) * 64 + hh] = a0;
    pDI[(size_t)(row0 + g*4 + 1) * 64 + hh] = a1;
    pDI[(size_t)(row0 + g*4 + 2) * 64 + hh] = a2;
    pDI[(size_t)(row0 + g*4 + 3) * 64 + hh] = a3;
  }

  f32x4 acc = {0.f, 0.f, 0.f, 0.f};
  int mA = t & 15;            // phase-A row
  int kg = t >> 4;            // phase-A k-group

  for (int chunk = 0; chunk < SEGLEN / KCH; chunk++) {   // 3 chunks of 256
    // ---- phase A: S for 16 rows x 256 pairs -> Sm (fp16, A-frag rows) ----
    #pragma unroll 4
    for (int j = 0; j < 16; j++) {
      int kc = kg * 16 + j;
      unsigned pb = pairsL[chunk * KCH + kc];
      int bI = pb & 0xFFFF, bJ = pb >> 16;
      float4 uv = *(const float4*)&xs[mA][bJ];
      float4 vv = *(const float4*)&xs[mA][bI];
      float u2[4] = { fmaf(2.f, uv.x, 1e-5f), fmaf(2.f, uv.y, 1e-5f),
                      fmaf(2.f, uv.z, 1e-5f), fmaf(2.f, uv.w, 1e-5f) };
      float u[4]  = { uv.x, uv.y, uv.z, uv.w };
      float v[4]  = { vv.x, vv.y, vv.z, vv.w };
      float s = 0.f;
      #pragma unroll
      for (int a = 0; a < 4; a++) {
        float va = v[a] + 1e-5f;
        #pragma unroll
        for (int b = 0; b < 4; b++)
          s = fmaf(u2[b], __builtin_amdgcn_rcpf(u[b] + va), s);
      }
      Sm[mA][kc] = (_Float16)(s - 16.f);
    }
    __syncthreads();

    // ---- phase B: 8 MFMA per wave (K=256), B-frags straight from global ----
    int kbase = k0 + chunk * KCH;
    #pragma unroll
    for (int c = 0; c < KCH / 32; c++) {
      f16x8 aF = *(const f16x8*)&Sm[n_in][c * 32 + quad * 8];
      f16x8 bF = *(const f16x8*)&wATt[(size_t)h * NPAIR_P + kbase + c * 32 + quad * 8];
      acc = __builtin_amdgcn_mfma_f32_16x16x32_f16(aF, bF, acc, 0, 0, 0);
    }
    __syncthreads();
  }

  // epilogue: D[m][n]: n = lane&15, m = quad*4 + reg
  #pragma unroll
  for (int r = 0; r < 4; r++) {
    int m = quad * 4 + r;
    pNDI[((size_t)seg * BATCH + row0 + m) * 64 + h] = acc[r];
  }
}

// ---------------------------------------------------------------------------
// tail: reduce K-partials, biases+elu, fcDI/fcNDI (64->48 each), concat(96),
// fc1(96->48), l1(48->20), l2(20->1), sigmoid. grid = 256 blocks.
// ---------------------------------------------------------------------------
__global__ __launch_bounds__(256) void fcr_tail_v4(
    const float* __restrict__ ws,
    const float* __restrict__ bDI,
    const float* __restrict__ fcDI_w,
    const float* __restrict__ fcDI_b,
    const float* __restrict__ bNDI,
    const float* __restrict__ fcNDI_w,
    const float* __restrict__ fcNDI_b,
    const float* __restrict__ fc1_w,
    const float* __restrict__ fc1_b,
    const float* __restrict__ l1_w,
    const float* __restrict__ l1_b,
    const float* __restrict__ l2_w,
    const float* __restrict__ l2_b,
    float* __restrict__ out) {
  __shared__ float wDT[HEAD * EMBD];   // [h][o]
  __shared__ float wNT[HEAD * EMBD];   // [h][o]
  __shared__ float w1T[96 * 48];       // [i][o]
  __shared__ float wl1T[48 * 20];      // [j][o]
  __shared__ float wl2s[20];
  __shared__ float bD[HEAD], bN[HEAD], bDe[EMBD], bNe[EMBD], b1[48], bl1s[20];
  __shared__ float bl2s;
  __shared__ float ehD[TB][68], ehN[TB][68];
  __shared__ float e2[TB][100];
  __shared__ float e3[TB][52];
  __shared__ float e4[TB][20];

  int t = threadIdx.x;
  for (int i = t; i < HEAD * EMBD; i += 256) {
    int o = i >> 6, hh = i & 63;               // fcDI_w[o][hh]
    wDT[hh * EMBD + o] = fcDI_w[i];
    wNT[hh * EMBD + o] = fcNDI_w[i];
  }
  for (int i = t; i < 48 * 96; i += 256) {
    int o = i / 96, j = i - o * 96;            // fc1_w[o][j]
    w1T[j * 48 + o] = fc1_w[i];
  }
  for (int i = t; i < 20 * 48; i += 256) {
    int o = i / 48, j = i - o * 48;            // l1_w[o][j]
    wl1T[j * 20 + o] = l1_w[i];
  }
  if (t < 20)   { wl2s[t] = l2_w[t]; bl1s[t] = l1_b[t]; }
  if (t < HEAD) { bD[t] = bDI[t]; bN[t] = bNDI[t]; }
  if (t < EMBD) { bDe[t] = fcDI_b[t]; bNe[t] = fcNDI_b[t]; }
  if (t < 48)   b1[t] = fc1_b[t];
  if (t == 0)   bl2s = l2_b[0];

  const float* pDI  = ws + WS_PDI;
  const float* pNDI = ws + WS_PNDI;
  int row0 = blockIdx.x * TB;
  __syncthreads();

  for (int i = t; i < TB * HEAD; i += 256) {
    int r = i >> 6, hh = i & 63;
    int row = row0 + r;
    float hD = pDI[(size_t)row * 64 + hh] + bD[hh];
    float hN = bN[hh];
    for (int s2 = 0; s2 < KSPLIT; s2++)
      hN += pNDI[((size_t)s2 * BATCH + row) * 64 + hh];
    ehD[r][hh] = eluf(hD);
    ehN[r][hh] = eluf(hN);
  }
  __syncthreads();

  for (int i = t; i < TB * 96; i += 256) {
    int r = i / 96, o = i - r * 96;
    int isN = o >= 48;
    int o2 = isN ? o - 48 : o;
    const float* wb = isN ? wNT : wDT;
    const float* eb = isN ? &ehN[r][0] : &ehD[r][0];
    float s = isN ? bNe[o2] : bDe[o2];
    for (int hh = 0; hh < 64; hh++)
      s = fmaf(eb[hh], wb[hh * EMBD + o2], s);
    e2[r][o] = eluf(s);
  }
  __syncthreads();

  for (int i = t; i < TB * 48; i += 256) {
    int r = i / 48, o = i - r * 48;
    float s = b1[o];
    for (int j = 0; j < 96; j++)
      s = fmaf(e2[r][j], w1T[j * 48 + o], s);
    e3[r][o] = eluf(s);
  }
  __syncthreads();

  if (t < TB * 20) {
    int r = t / 20, o = t - r * 20;
    float s = bl1s[o];
    for (int j = 0; j < 48; j++)
      s = fmaf(e3[r][j], wl1T[j * 20 + o], s);
    e4[r][o] = eluf(s);
  }
  __syncthreads();

  if (t < TB) {
    float s = bl2s;
    for (int j = 0; j < 20; j++)
      s = fmaf(e4[t][j], wl2s[j], s);
    out[row0 + t] = 1.f / (1.f + expf(-s));
  }
}

extern "C" void kernel_launch(void* const* d_in, const int* in_sizes, int n_in,
                              void* d_out, int out_size, void* d_ws, size_t ws_size,
                              hipStream_t stream) {
  const float* x      = (const float*)d_in[0];
  const float* wDI    = (const float*)d_in[1];
  const float* bDI    = (const float*)d_in[2];
  const float* fcDI_w = (const float*)d_in[3];
  const float* fcDI_b = (const float*)d_in[4];
  const float* wNDI   = (const float*)d_in[5];
  const float* bNDI   = (const float*)d_in[6];
  const float* fcNDI_w= (const float*)d_in[7];
  const float* fcNDI_b= (const float*)d_in[8];
  const float* fc1_w  = (const float*)d_in[9];
  const float* fc1_b  = (const float*)d_in[10];
  const float* l1_w   = (const float*)d_in[11];
  const float* l1_b   = (const float*)d_in[12];
  const float* l2_w   = (const float*)d_in[13];
  const float* l2_b   = (const float*)d_in[14];
  float* out = (float*)d_out;
  float* ws = (float*)d_ws;   // 3.05 MB used

  fcr_prep_v4<<<HEAD, 256, 0, stream>>>(wDI, wNDI, ws);
  fcr_main_v4<<<(BATCH / MROWS) * KSPLIT, 256, 0, stream>>>(x, ws);
  fcr_tail_v4<<<BATCH / TB, 256, 0, stream>>>(ws, bDI, fcDI_w, fcDI_b,
      bNDI, fcNDI_w, fcNDI_b, fc1_w, fc1_b, l1_w, l1_b, l2_w, l2_b, out);
}